// Round 1
// baseline (276.628 us; speedup 1.0000x reference)
//
#include <hip/hip_runtime.h>
#include <cstdint>
#include <cstddef>

#define NH 16
#define ND 64
#define NK 256
#define NE 8
#define NV 196608
#define NBL 16384           // B*L = 4*4096
#define MS 68               // padded LDS row stride for means (floats)

struct Primes { int p[NH]; };

// ---------------- K1: PQ assignment + EMA accumulation + normed_x ----------------
__global__ __launch_bounds__(256) void k_pq(
    const float* __restrict__ x, const float* __restrict__ means,
    const float* __restrict__ lnxs, const float* __restrict__ lnxb,
    float* __restrict__ out, uint8_t* __restrict__ cids,
    float* __restrict__ gsum, int* __restrict__ gcnt)
{
  __shared__ float sm[NK * MS];   // means rows (padded); later reused as [64][256] accum
  __shared__ float smsq[NK];
  __shared__ int   scnt[NK];
  __shared__ float ssc[ND], sbi[ND];

  const int tid = threadIdx.x;
  const int h   = blockIdx.y;

  // stage means row k=tid for head h; compute m_sq
  {
    const float4* mr = (const float4*)(means + ((size_t)h * NK + tid) * ND);
    float4* dst = (float4*)(sm + tid * MS);
    float msq = 0.f;
#pragma unroll
    for (int i = 0; i < 16; ++i) {
      float4 v = mr[i];
      dst[i] = v;
      msq += v.x * v.x + v.y * v.y + v.z * v.z + v.w * v.w;
    }
    smsq[tid] = msq;
  }
  if (tid < ND) { ssc[tid] = lnxs[h * ND + tid]; sbi[tid] = lnxb[h * ND + tid]; }
  __syncthreads();

  // load x for token g, head h into registers
  const int g = blockIdx.x * 256 + tid;          // token index in [0, NBL)
  const float4* xr4 = (const float4*)(x + ((size_t)g * NH + h) * ND);
  float4 xr[16];
  float xsq = 0.f, xsum = 0.f;
#pragma unroll
  for (int i = 0; i < 16; ++i) {
    float4 v = xr4[i];
    xr[i] = v;
    xsq  += v.x * v.x + v.y * v.y + v.z * v.z + v.w * v.w;
    xsum += v.x + v.y + v.z + v.w;
  }

  // argmin over 256 clusters: dist = (x_sq + m_sq) - 2*dot
  float best = 3.4e38f;
  int bk = 0;
#pragma unroll 2
  for (int k = 0; k < NK; ++k) {
    const float4* m4 = (const float4*)(sm + k * MS);
    float ax = 0.f, ay = 0.f, az = 0.f, aw = 0.f;
#pragma unroll
    for (int i = 0; i < 16; ++i) {
      float4 m = m4[i];
      ax = fmaf(xr[i].x, m.x, ax);
      ay = fmaf(xr[i].y, m.y, ay);
      az = fmaf(xr[i].z, m.z, az);
      aw = fmaf(xr[i].w, m.w, aw);
    }
    float dot  = (ax + ay) + (az + aw);
    float dist = (xsq + smsq[k]) - 2.0f * dot;
    if (dist < best) { best = dist; bk = k; }   // strict < => first-index tie-break
  }
  cids[(size_t)g * NH + h] = (uint8_t)bk;

  // normed_x -> out features [0,56)
  {
    float mu  = xsum * (1.f / 64.f);
    float var = xsq * (1.f / 64.f) - mu * mu;
    float rs  = rsqrtf(var + 1e-5f);
    float* orow = out + ((size_t)g * NH + h) * ND;
#pragma unroll
    for (int i = 0; i < 14; ++i) {             // 14*4 = 56 features
      float4 v = xr[i];
      float4 o;
      o.x = (v.x - mu) * rs * ssc[4 * i + 0] + sbi[4 * i + 0];
      o.y = (v.y - mu) * rs * ssc[4 * i + 1] + sbi[4 * i + 1];
      o.z = (v.z - mu) * rs * ssc[4 * i + 2] + sbi[4 * i + 2];
      o.w = (v.w - mu) * rs * ssc[4 * i + 3] + sbi[4 * i + 3];
      ((float4*)orow)[i] = o;
    }
  }

  // EMA accumulation: reuse sm as accum[64][256] (d-major so lanes hit distinct banks)
  __syncthreads();
#pragma unroll
  for (int d = 0; d < ND; ++d) sm[d * NK + tid] = 0.f;
  scnt[tid] = 0;
  __syncthreads();

  atomicAdd(&scnt[bk], 1);
#pragma unroll
  for (int i = 0; i < 16; ++i) {
    atomicAdd(&sm[(4 * i + 0) * NK + bk], xr[i].x);
    atomicAdd(&sm[(4 * i + 1) * NK + bk], xr[i].y);
    atomicAdd(&sm[(4 * i + 2) * NK + bk], xr[i].z);
    atomicAdd(&sm[(4 * i + 3) * NK + bk], xr[i].w);
  }
  __syncthreads();

  // flush: lane tid owns cluster k=tid; skip empty clusters; coalesced atomics
  const int cnt = scnt[tid];
  if (cnt > 0) atomicAdd(&gcnt[h * NK + tid], cnt);
  const bool act = cnt > 0;
#pragma unroll 4
  for (int d = 0; d < ND; ++d) {
    if (act) atomicAdd(&gsum[((size_t)h * ND + d) * NK + tid], sm[d * NK + tid]);
  }
}

// ---------------- K2: bigram hash + embedding gather + LN_y -> out[56:64) ----------------
__global__ __launch_bounds__(256) void k_ngram(
    const uint8_t* __restrict__ cids, const float* __restrict__ embed,
    const float* __restrict__ lys, const float* __restrict__ lyb,
    float* __restrict__ out, Primes pr)
{
  const int i = blockIdx.x * 256 + threadIdx.x;  // 0 .. NBL*NH-1
  const int h = i & 15;
  const int g = i >> 4;
  const int l = g & 4095;                        // L = 4096

  int cid  = (int)cids[i];
  int prev = (l == 0) ? 0 : (int)cids[i - NH];
  int ng   = cid + (prev << 8);                  // cid + prev*NUM_CLUSTERS
  int hp1  = h + 1;
  int v    = ng * hp1 + hp1;                     // <= ~1.05M, fits int32
  const int p = pr.p[h];
  while (v >= p) v -= p;                         // v % prime (v/p <= 5)
  if (v >= NV) v -= NV;                          // % NGRAM_VOCAB (v < 2*NV)

  const float4* e4 = (const float4*)(embed + ((size_t)(v + NV * h)) * NE);
  float4 y0 = e4[0], y1 = e4[1];

  float s = ((y0.x + y0.y) + (y0.z + y0.w)) + ((y1.x + y1.y) + (y1.z + y1.w));
  float mu = s * 0.125f;
  float q = y0.x * y0.x + y0.y * y0.y + y0.z * y0.z + y0.w * y0.w
          + y1.x * y1.x + y1.y * y1.y + y1.z * y1.z + y1.w * y1.w;
  float var = q * 0.125f - mu * mu;
  float rs  = rsqrtf(var + 1e-5f);

  const float* sc = lys + h * NE;
  const float* bi = lyb + h * NE;
  float4 o0, o1;
  o0.x = (y0.x - mu) * rs * sc[0] + bi[0];
  o0.y = (y0.y - mu) * rs * sc[1] + bi[1];
  o0.z = (y0.z - mu) * rs * sc[2] + bi[2];
  o0.w = (y0.w - mu) * rs * sc[3] + bi[3];
  o1.x = (y1.x - mu) * rs * sc[4] + bi[4];
  o1.y = (y1.y - mu) * rs * sc[5] + bi[5];
  o1.z = (y1.z - mu) * rs * sc[6] + bi[6];
  o1.w = (y1.w - mu) * rs * sc[7] + bi[7];

  float4* orow = (float4*)(out + ((size_t)g * NH + h) * ND + 56);
  orow[0] = o0;
  orow[1] = o1;
}

// ---------------- K3: finalize new_means ----------------
__global__ __launch_bounds__(256) void k_means(
    const float* __restrict__ means, const float* __restrict__ gsum,
    const int* __restrict__ gcnt, float* __restrict__ newm)
{
  const int i = blockIdx.x * 256 + threadIdx.x;  // 0 .. H*K*D-1, flat [h][k][d]
  const int d = i & 63;
  const int k = (i >> 6) & 255;
  const int h = i >> 14;
  float cnt = (float)gcnt[h * NK + k];
  float sx  = gsum[((size_t)h * ND + d) * NK + k];
  float mx  = sx / (1e-6f + cnt);
  const float omd = (float)(1.0 - 0.999);        // matches jax's f32(1.0-DECAY)
  newm[i] = omd * mx + 0.999f * means[i];
}

extern "C" void kernel_launch(void* const* d_in, const int* in_sizes, int n_in,
                              void* d_out, int out_size, void* d_ws, size_t ws_size,
                              hipStream_t stream)
{
  const float* x     = (const float*)d_in[0];
  const float* means = (const float*)d_in[1];
  const float* embed = (const float*)d_in[2];
  const float* lnxs  = (const float*)d_in[3];
  const float* lnxb  = (const float*)d_in[4];
  const float* lys   = (const float*)d_in[5];
  const float* lyb   = (const float*)d_in[6];

  float* out  = (float*)d_out;
  float* newm = out + (size_t)NBL * NH * ND;     // out tensor is 16777216 floats

  // workspace layout: gsum [16][64][256] f32 (1MB) | gcnt [16][256] i32 (16KB) | cids [NBL][NH] u8 (256KB)
  float*   gsum = (float*)d_ws;
  int*     gcnt = (int*)((char*)d_ws + (size_t)NH * NK * ND * 4);
  uint8_t* cids = (uint8_t*)((char*)d_ws + (size_t)NH * NK * ND * 4 + (size_t)NH * NK * 4);

  hipMemsetAsync(d_ws, 0, (size_t)NH * NK * ND * 4 + (size_t)NH * NK * 4, stream);

  // first NH primes > NGRAM_VOCAB (matches reference _first_primes_after)
  Primes pr;
  {
    int n = NV, c = 0;
    while (c < NH) {
      ++n;
      bool isp = true;
      for (int q = 2; (long long)q * q <= n; ++q)
        if (n % q == 0) { isp = false; break; }
      if (isp) pr.p[c++] = n;
    }
  }

  dim3 g1(NBL / 256, NH);
  k_pq<<<g1, 256, 0, stream>>>(x, means, lnxs, lnxb, out, cids, gsum, gcnt);
  k_ngram<<<(NBL * NH) / 256, 256, 0, stream>>>(cids, embed, lys, lyb, out, pr);
  k_means<<<(NH * NK * ND) / 256, 256, 0, stream>>>(means, gsum, gcnt, newm);
}